// Round 14
// baseline (321.747 us; speedup 1.0000x reference)
//
#include <hip/hip_runtime.h>
#include <math.h>

// SSIM 1D loss: B=16, C=32, T=48000, window=11, sigma=1.5, zero padding.
// u/v reformulation: 4 convs (u, v, u^2, v^2) recover all SSIM moments.
//
// R14 = R9 structure with:
//  (a) OPT=4: ONE f32x4 per stream per thread -> every wave-load is a fully
//      lane-dense 1KB transaction (R8/R9's 32B-stride pairs were half-dense;
//      m13's 6.3TB/s copy uses dense loads). Tests "line density caps BW".
//  (b) no reduce kernel: per-block partial atomicAdd'ed into out[0]
//      (native f32 device-scope atomic, NO threadfence -- R10's mistake was
//      the fence, not the atomic). out zeroed via graph-captured memsetAsync;
//      block 0 contributes the leading 1.0. FP-order noise ~1e-7 << 2e-2.
constexpr int T     = 48000;
constexpr int TPB   = 256;
constexpr int OPT   = 4;            // outputs per thread
constexpr int TPROW = T / OPT;      // 12000 threads per row (exact)
constexpr float C1f = 0.0001f;      // 0.01^2
constexpr float C2f = 0.0009f;      // 0.03^2

typedef float f32x4 __attribute__((ext_vector_type(4)));

struct W11 { float w[11]; };

__global__ __launch_bounds__(TPB, 8) void ssim_main(
    const float* __restrict__ pred, const float* __restrict__ targ,
    float* __restrict__ out, float inv_n, W11 wts)
{
    const int tid  = blockIdx.x * TPB + (int)threadIdx.x;   // grid exact
    const int lane = threadIdx.x & 63;
    const int rp   = (tid % TPROW) * OPT;                   // pos within row
    const size_t base = (size_t)tid * OPT;                  // flat first output

    // ---- own data: exactly x[base .. base+3], fully lane-dense ----
    const f32x4 p0 = *reinterpret_cast<const f32x4*>(pred + base);
    const f32x4 q0 = *reinterpret_cast<const f32x4*>(targ + base);
    const f32x4 u0 = p0 + q0;
    const f32x4 v0 = p0 - q0;

    // window w=0..13 <-> x[base-5+w]; own elements at w=5..8
    float U[14], V[14];
    U[5]=u0.x; U[6]=u0.y; U[7]=u0.z; U[8]=u0.w;
    V[5]=v0.x; V[6]=v0.y; V[7]=v0.z; V[8]=v0.w;

    // ---- halo via shuffles (all lanes active) ----
    U[1]=__shfl_up(u0.x,1); U[2]=__shfl_up(u0.y,1); U[3]=__shfl_up(u0.z,1); U[4]=__shfl_up(u0.w,1);
    V[1]=__shfl_up(v0.x,1); V[2]=__shfl_up(v0.y,1); V[3]=__shfl_up(v0.z,1); V[4]=__shfl_up(v0.w,1);
    U[0]=__shfl_up(u0.w,2);  V[0]=__shfl_up(v0.w,2);        // x[base-5] from lane-2
    U[9]=__shfl_down(u0.x,1); U[10]=__shfl_down(u0.y,1); U[11]=__shfl_down(u0.z,1); U[12]=__shfl_down(u0.w,1);
    V[9]=__shfl_down(v0.x,1); V[10]=__shfl_down(v0.y,1); V[11]=__shfl_down(v0.z,1); V[12]=__shfl_down(v0.w,1);
    U[13]=__shfl_down(u0.x,2); V[13]=__shfl_down(v0.x,2);   // x[base+8] from lane+2

    // ---- wave-edge lanes: patch row-valid elements from global (masked) ----
    auto patch = [&](int w) {
        const int g = rp + (w - 5);                         // position within row
        if (g >= 0 && g < T) {
            const float a = pred[base + (w - 5)];
            const float b = targ[base + (w - 5)];
            U[w] = a + b; V[w] = a - b;
        }
    };
    if (lane == 0)       { patch(0); patch(1); patch(2); patch(3); patch(4); }
    else if (lane == 1)  { patch(0); }
    if (lane == 63)      { patch(9); patch(10); patch(11); patch(12); patch(13); }
    else if (lane == 62) { patch(13); }

    // ---- row-boundary zero-fill (lax zero padding); halo(5) > OPT(4), so
    //      the 2nd/2nd-last thread of each row also cross the boundary ----
    if (rp == 0) {
        U[0]=0.f; U[1]=0.f; U[2]=0.f; U[3]=0.f; U[4]=0.f;
        V[0]=0.f; V[1]=0.f; V[2]=0.f; V[3]=0.f; V[4]=0.f;
    } else if (rp == OPT) {            // rp==4: x[base-5] is previous row
        U[0]=0.f; V[0]=0.f;
    }
    if (rp == T - OPT) {
        U[9]=0.f; U[10]=0.f; U[11]=0.f; U[12]=0.f; U[13]=0.f;
        V[9]=0.f; V[10]=0.f; V[11]=0.f; V[12]=0.f; V[13]=0.f;
    } else if (rp == T - 2 * OPT) {    // rp==T-8: x[base+8] is next row
        U[13]=0.f; V[13]=0.f;
    }

    // ---- w-outer consume: transient squares, small live set ----
    // output m uses window w = m+k (tap k = w-m in [0,10])
    float cu[OPT] = {}, cv[OPT] = {}, cuu[OPT] = {}, cvv[OPT] = {};
    #pragma unroll
    for (int w = 0; w < 14; w++) {
        const float u = U[w], v = V[w];
        const float uu = u * u, vv = v * v;
        #pragma unroll
        for (int m = 0; m < OPT; m++) {
            const int k = w - m;
            if (k < 0 || k > 10) continue;
            const float wk = wts.w[k];                      // SGPR
            cu[m]  = fmaf(wk, u,  cu[m]);
            cv[m]  = fmaf(wk, v,  cv[m]);
            cuu[m] = fmaf(wk, uu, cuu[m]);
            cvv[m] = fmaf(wk, vv, cvv[m]);
        }
    }

    // ---- SSIM epilogue ----
    float qsum = 0.f;
    #pragma unroll
    for (int m = 0; m < OPT; m++) {
        const float aa = cu[m] * cu[m], bb = cv[m] * cv[m];
        const float e  = 0.5f * (aa - bb);                  // 2*mu1*mu2
        const float f  = 0.5f * (aa + bb);                  // mu1^2+mu2^2
        const float t2 = 0.5f * (cuu[m] - cvv[m]);          // 2*s12
        const float sP = 0.5f * (cuu[m] + cvv[m]);          // s11+s22
        const float num = (e + C1f) * (t2 - e + C2f);
        const float den = (f + C1f) * (sP - f + C2f);
        qsum += num * __builtin_amdgcn_rcpf(den);           // den >= C1*C2 > 0
    }

    // ---- block reduction -> one atomic per block ----
    #pragma unroll
    for (int off = 32; off; off >>= 1) qsum += __shfl_down(qsum, off);
    __shared__ float wsum[TPB / 64];
    if ((threadIdx.x & 63) == 0) wsum[threadIdx.x >> 6] = qsum;
    __syncthreads();
    if (threadIdx.x == 0) {
        float s = 0.f;
        #pragma unroll
        for (int i = 0; i < TPB / 64; i++) s += wsum[i];
        // out[0] accumulates 1 - sum(ssim)/n across blocks; block 0 adds the 1.
        const float add = -s * inv_n + (blockIdx.x == 0 ? 1.0f : 0.0f);
        atomicAdd(out, add);                                // device-scope, no fence
    }
}

extern "C" void kernel_launch(void* const* d_in, const int* in_sizes, int n_in,
                              void* d_out, int out_size, void* d_ws, size_t ws_size,
                              hipStream_t stream)
{
    const float* pred = (const float*)d_in[0];
    const float* targ = (const float*)d_in[1];
    float* out = (float*)d_out;

    const int n      = in_sizes[0];               // B*C*T = 24,576,000
    const int blocks = n / OPT / TPB;             // 24,000 exactly

    // Gaussian window computed on host in double (matches numpy), cast to f32.
    W11 wts;
    double g[11], s = 0.0;
    for (int i = 0; i < 11; i++) { g[i] = exp(-((i - 5) * (i - 5)) / 4.5); s += g[i]; }
    for (int i = 0; i < 11; i++) wts.w[i] = (float)(g[i] / s);

    hipMemsetAsync(out, 0, sizeof(float), stream);          // graph-capturable
    hipLaunchKernelGGL(ssim_main, dim3(blocks), dim3(TPB), 0, stream,
                       pred, targ, out, 1.0f / (float)n, wts);
}

// Round 15
// 52.959 us; speedup vs baseline: 6.0754x; 6.0754x over previous
//
#include <hip/hip_runtime.h>
#include <math.h>

// SSIM 1D loss: B=16, C=32, T=48000, window=11, sigma=1.5, zero padding.
// u/v reformulation: 4 convs (u, v, u^2, v^2) recover all SSIM moments.
//
// R15 = R9 + NON-TEMPORAL pred stream (single-variable change).
// Theory: inputs (196.6MB) nearly fill the 256MB L3; streaming both self-
// evicts to ~50% hit, and the line-granular interleaved HBM miss stream runs
// at only ~2.2 TB/s (row-buffer-hostile). Partition instead: pred marked nt
// (not retained in L3) -> targ (98MB) becomes fully L3-resident across graph
// replays; pred is a pure dense sequential HBM stream (~6.3 TB/s).
// R7's nt regression was the 3-5x-redundant windowed loads losing cache reuse;
// R9's own-data loads have zero reuse, so nt is free here.
constexpr int T     = 48000;
constexpr int TPB   = 256;
constexpr int OPT   = 8;            // outputs per thread
constexpr int TPROW = T / OPT;      // 6000 threads per row (exact)
constexpr float C1f = 0.0001f;      // 0.01^2
constexpr float C2f = 0.0009f;      // 0.03^2

typedef float f32x2 __attribute__((ext_vector_type(2)));
typedef float f32x4 __attribute__((ext_vector_type(4)));

struct WP { f32x2 wp[12]; };        // wp[j] = {g[j], g[j-1]}, 0 outside [0,10]

__global__ __launch_bounds__(TPB, 8) void ssim_main(
    const float* __restrict__ pred, const float* __restrict__ targ,
    float* __restrict__ partial, WP wts)
{
    const int tid  = blockIdx.x * TPB + (int)threadIdx.x;   // grid exact
    const int lane = threadIdx.x & 63;
    const int rp   = (tid % TPROW) * OPT;                   // pos within row
    const size_t base = (size_t)tid * OPT;                  // flat first output

    // ---- own data: exactly x[base .. base+7], unit-stride coalesced ----
    // pred: non-temporal (pure HBM stream, not retained in L3)
    // targ: cached (98MB -> fully L3-resident across replays)
    const f32x4* P4 = reinterpret_cast<const f32x4*>(pred + base);
    const f32x4* Q4 = reinterpret_cast<const f32x4*>(targ + base);
    const f32x4 p0 = __builtin_nontemporal_load(P4);
    const f32x4 p1 = __builtin_nontemporal_load(P4 + 1);
    const f32x4 q0 = Q4[0], q1 = Q4[1];
    const f32x4 u0 = p0 + q0, u1 = p1 + q1;
    const f32x4 v0 = p0 - q0, v1 = p1 - q1;

    // window index w=0..17 <-> x[base-5+w]; own j=0..7 at w=5+j
    float U[18], V[18];
    U[5]=u0.x; U[6]=u0.y; U[7]=u0.z; U[8]=u0.w; U[9]=u1.x; U[10]=u1.y; U[11]=u1.z; U[12]=u1.w;
    V[5]=v0.x; V[6]=v0.y; V[7]=v0.z; V[8]=v0.w; V[9]=v1.x; V[10]=v1.y; V[11]=v1.z; V[12]=v1.w;

    // ---- halo via shuffles (all lanes active here) ----
    #pragma unroll
    for (int j = 0; j < 5; j++) {                 // left: prev thread's w=8+j
        U[j] = __shfl_up(U[8 + j], 1);
        V[j] = __shfl_up(V[8 + j], 1);
    }
    #pragma unroll
    for (int j = 0; j < 5; j++) {                 // right: next thread's w=5+j
        U[13 + j] = __shfl_down(U[5 + j], 1);
        V[13 + j] = __shfl_down(V[5 + j], 1);
    }

    const bool leftEdge  = (rp == 0);
    const bool rightEdge = (rp == T - OPT);

    // wave-edge lanes: shuffle source invalid -> patch from global
    if (lane == 0 && !leftEdge) {                 // x[base-8 .. base-1], use [3..7]
        const f32x4 a0 = reinterpret_cast<const f32x4*>(pred + base - 8)[0];
        const f32x4 a1 = reinterpret_cast<const f32x4*>(pred + base - 8)[1];
        const f32x4 b0 = reinterpret_cast<const f32x4*>(targ + base - 8)[0];
        const f32x4 b1 = reinterpret_cast<const f32x4*>(targ + base - 8)[1];
        U[0]=a0.w+b0.w; V[0]=a0.w-b0.w;
        U[1]=a1.x+b1.x; V[1]=a1.x-b1.x;
        U[2]=a1.y+b1.y; V[2]=a1.y-b1.y;
        U[3]=a1.z+b1.z; V[3]=a1.z-b1.z;
        U[4]=a1.w+b1.w; V[4]=a1.w-b1.w;
    }
    if (lane == 63 && !rightEdge) {               // x[base+8 .. base+15], use [0..4]
        const f32x4 c0 = reinterpret_cast<const f32x4*>(pred + base + 8)[0];
        const f32x4 c1 = reinterpret_cast<const f32x4*>(pred + base + 8)[1];
        const f32x4 d0 = reinterpret_cast<const f32x4*>(targ + base + 8)[0];
        const f32x4 d1 = reinterpret_cast<const f32x4*>(targ + base + 8)[1];
        U[13]=c0.x+d0.x; V[13]=c0.x-d0.x;
        U[14]=c0.y+d0.y; V[14]=c0.y-d0.y;
        U[15]=c0.z+d0.z; V[15]=c0.z-d0.z;
        U[16]=c0.w+d0.w; V[16]=c0.w-d0.w;
        U[17]=c1.x+d1.x; V[17]=c1.x-d1.x;
    }
    if (leftEdge) {                               // zero pad (row start)
        #pragma unroll
        for (int j = 0; j < 5; j++) { U[j] = 0.f; V[j] = 0.f; }
    }
    if (rightEdge) {                              // zero pad (row end)
        #pragma unroll
        for (int j = 13; j < 18; j++) { U[j] = 0.f; V[j] = 0.f; }
    }

    // ---- consume: window w contributes weight g[w-m] to output m ----
    // output pair (2p,2p+1): j = w-2p, weights wp[j] = {g[j], g[j-1]}, j in [0,11]
    f32x2 cA[4] = {}, cB[4] = {}, cC[4] = {}, cD[4] = {};
    #pragma unroll
    for (int w = 0; w < 18; w++) {
        const float u  = U[w], v = V[w];
        const float uu = u * u, vv = v * v;
        #pragma unroll
        for (int p = 0; p < 4; p++) {
            const int j = w - 2 * p;
            if (j < 0 || j > 11) continue;
            const f32x2 wp = wts.wp[j];
            cA[p] += u  * wp;
            cB[p] += v  * wp;
            cC[p] += uu * wp;
            cD[p] += vv * wp;
        }
    }

    // ---- packed SSIM epilogue ----
    float qsum = 0.f;
    #pragma unroll
    for (int p = 0; p < 4; p++) {
        const f32x2 aa = cA[p] * cA[p], bb = cB[p] * cB[p];
        const f32x2 e   = 0.5f * (aa - bb);       // 2*mu1*mu2
        const f32x2 f2  = 0.5f * (aa + bb);       // mu1^2+mu2^2
        const f32x2 t2  = 0.5f * (cC[p] - cD[p]); // 2*s12
        const f32x2 sP  = 0.5f * (cC[p] + cD[p]); // s11+s22
        const f32x2 num = (e + C1f) * (t2 - e + C2f);
        const f32x2 den = (f2 + C1f) * (sP - f2 + C2f);
        qsum += num.x * __builtin_amdgcn_rcpf(den.x);   // den >= C1*C2 > 0
        qsum += num.y * __builtin_amdgcn_rcpf(den.y);
    }

    // ---- block reduction -> one partial per block ----
    #pragma unroll
    for (int off = 32; off; off >>= 1) qsum += __shfl_down(qsum, off);
    __shared__ float wsum[TPB / 64];
    if ((threadIdx.x & 63) == 0) wsum[threadIdx.x >> 6] = qsum;
    __syncthreads();
    if (threadIdx.x == 0) {
        float s = 0.f;
        #pragma unroll
        for (int i = 0; i < TPB / 64; i++) s += wsum[i];
        partial[blockIdx.x] = s;
    }
}

__global__ __launch_bounds__(256) void ssim_reduce(
    const f32x4* __restrict__ partial4, int n4, float* __restrict__ out, float inv_n)
{
    float s = 0.f;
    for (int i = threadIdx.x; i < n4; i += 256) {
        const f32x4 p = partial4[i];
        s += (p.x + p.y) + (p.z + p.w);
    }
    #pragma unroll
    for (int off = 32; off; off >>= 1) s += __shfl_down(s, off);
    __shared__ float ws[4];
    if ((threadIdx.x & 63) == 0) ws[threadIdx.x >> 6] = s;
    __syncthreads();
    if (threadIdx.x == 0) {
        float t = 0.f;
        #pragma unroll
        for (int i = 0; i < 4; i++) t += ws[i];
        out[0] = 1.f - t * inv_n;                 // mean(1-ssim) = 1 - mean(ssim)
    }
}

extern "C" void kernel_launch(void* const* d_in, const int* in_sizes, int n_in,
                              void* d_out, int out_size, void* d_ws, size_t ws_size,
                              hipStream_t stream)
{
    const float* pred = (const float*)d_in[0];
    const float* targ = (const float*)d_in[1];
    float* out = (float*)d_out;
    float* partial = (float*)d_ws;

    const int n      = in_sizes[0];               // B*C*T = 24,576,000
    const int blocks = n / OPT / TPB;             // 12,000 exactly (48 KB d_ws)

    // Gaussian window on host in double (matches numpy), then adjacent pairs.
    double g[11], s = 0.0;
    for (int i = 0; i < 11; i++) { g[i] = exp(-((i - 5) * (i - 5)) / 4.5); s += g[i]; }
    float gw[11];
    for (int i = 0; i < 11; i++) gw[i] = (float)(g[i] / s);
    WP wts;
    for (int j = 0; j < 12; j++) {
        wts.wp[j].x = (j <= 10) ? gw[j] : 0.f;
        wts.wp[j].y = (j >= 1) ? gw[j - 1] : 0.f;
    }

    hipLaunchKernelGGL(ssim_main, dim3(blocks), dim3(TPB), 0, stream,
                       pred, targ, partial, wts);
    hipLaunchKernelGGL(ssim_reduce, dim3(1), dim3(256), 0, stream,
                       (const f32x4*)partial, blocks / 4, out, 1.0f / (float)n);
}

// Round 16
// 49.317 us; speedup vs baseline: 6.5240x; 1.0739x over previous
//
#include <hip/hip_runtime.h>
#include <math.h>

// SSIM 1D loss: B=16, C=32, T=48000, window=11, sigma=1.5, zero padding.
// u/v reformulation: 4 convs (u, v, u^2, v^2) recover all SSIM moments.
//
// R16 = R8 exact revert (best measured: 49.38us total).
// Final structure: perfect coalescing -- each thread loads exactly its own
// 8 elements per stream (2 aligned float4, zero redundancy; wave-loads are
// line-dense), halo via wave shuffles, row edges zero-filled (= lax zero
// padding), w-outer consume with paired weights, two-kernel deterministic
// reduction. Probes measured null/negative around this point: occupancy
// (6->8 waves, VGPR 40->32), grid-stride ILP, v_pk_fma (both axes),
// nontemporal loads (3 variants), L3 partitioning, fused-finish (fence AND
// atomic forms -- both catastrophic on gfx950's non-coherent XCD L2s).
// Verdict: memory-path-bound at ~4.5 TB/s combined (197MB unique, ~50%
// L3-resident) with VALU (~27us) fully overlapped; practical roofline.
constexpr int T     = 48000;
constexpr int TPB   = 256;
constexpr int OPT   = 8;            // outputs per thread
constexpr int TPROW = T / OPT;      // 6000 threads per row (exact)
constexpr float C1f = 0.0001f;      // 0.01^2
constexpr float C2f = 0.0009f;      // 0.03^2

typedef float f32x2 __attribute__((ext_vector_type(2)));
typedef float f32x4 __attribute__((ext_vector_type(4)));

struct WP { f32x2 wp[12]; };        // wp[j] = {g[j], g[j-1]}, 0 outside [0,10]

__global__ __launch_bounds__(TPB, 6) void ssim_main(
    const float* __restrict__ pred, const float* __restrict__ targ,
    float* __restrict__ partial, WP wts)
{
    const int tid  = blockIdx.x * TPB + (int)threadIdx.x;   // grid exact
    const int lane = threadIdx.x & 63;
    const int rp   = (tid % TPROW) * OPT;                   // pos within row
    const size_t base = (size_t)tid * OPT;                  // flat first output

    // ---- own data: exactly x[base .. base+7], unit-stride coalesced ----
    const f32x4* P4 = reinterpret_cast<const f32x4*>(pred + base);
    const f32x4* Q4 = reinterpret_cast<const f32x4*>(targ + base);
    const f32x4 p0 = P4[0], p1 = P4[1];
    const f32x4 q0 = Q4[0], q1 = Q4[1];
    const f32x4 u0 = p0 + q0, u1 = p1 + q1;
    const f32x4 v0 = p0 - q0, v1 = p1 - q1;

    // window index w=0..17 <-> x[base-5+w]; own j=0..7 at w=5+j
    float U[18], V[18];
    U[5]=u0.x; U[6]=u0.y; U[7]=u0.z; U[8]=u0.w; U[9]=u1.x; U[10]=u1.y; U[11]=u1.z; U[12]=u1.w;
    V[5]=v0.x; V[6]=v0.y; V[7]=v0.z; V[8]=v0.w; V[9]=v1.x; V[10]=v1.y; V[11]=v1.z; V[12]=v1.w;

    // ---- halo via shuffles (all lanes active here) ----
    #pragma unroll
    for (int j = 0; j < 5; j++) {                 // left: prev thread's w=8+j
        U[j] = __shfl_up(U[8 + j], 1);
        V[j] = __shfl_up(V[8 + j], 1);
    }
    #pragma unroll
    for (int j = 0; j < 5; j++) {                 // right: next thread's w=5+j
        U[13 + j] = __shfl_down(U[5 + j], 1);
        V[13 + j] = __shfl_down(V[5 + j], 1);
    }

    const bool leftEdge  = (rp == 0);
    const bool rightEdge = (rp == T - OPT);

    // wave-edge lanes: shuffle source invalid -> patch from global
    if (lane == 0 && !leftEdge) {                 // x[base-8 .. base-1], use [3..7]
        const f32x4 a0 = reinterpret_cast<const f32x4*>(pred + base - 8)[0];
        const f32x4 a1 = reinterpret_cast<const f32x4*>(pred + base - 8)[1];
        const f32x4 b0 = reinterpret_cast<const f32x4*>(targ + base - 8)[0];
        const f32x4 b1 = reinterpret_cast<const f32x4*>(targ + base - 8)[1];
        U[0]=a0.w+b0.w; V[0]=a0.w-b0.w;
        U[1]=a1.x+b1.x; V[1]=a1.x-b1.x;
        U[2]=a1.y+b1.y; V[2]=a1.y-b1.y;
        U[3]=a1.z+b1.z; V[3]=a1.z-b1.z;
        U[4]=a1.w+b1.w; V[4]=a1.w-b1.w;
    }
    if (lane == 63 && !rightEdge) {               // x[base+8 .. base+15], use [0..4]
        const f32x4 c0 = reinterpret_cast<const f32x4*>(pred + base + 8)[0];
        const f32x4 c1 = reinterpret_cast<const f32x4*>(pred + base + 8)[1];
        const f32x4 d0 = reinterpret_cast<const f32x4*>(targ + base + 8)[0];
        const f32x4 d1 = reinterpret_cast<const f32x4*>(targ + base + 8)[1];
        U[13]=c0.x+d0.x; V[13]=c0.x-d0.x;
        U[14]=c0.y+d0.y; V[14]=c0.y-d0.y;
        U[15]=c0.z+d0.z; V[15]=c0.z-d0.z;
        U[16]=c0.w+d0.w; V[16]=c0.w-d0.w;
        U[17]=c1.x+d1.x; V[17]=c1.x-d1.x;
    }
    if (leftEdge) {                               // zero pad (row start)
        #pragma unroll
        for (int j = 0; j < 5; j++) { U[j] = 0.f; V[j] = 0.f; }
    }
    if (rightEdge) {                              // zero pad (row end)
        #pragma unroll
        for (int j = 13; j < 18; j++) { U[j] = 0.f; V[j] = 0.f; }
    }

    // ---- consume: window w contributes weight g[w-m] to output m ----
    // output pair (2p,2p+1): j = w-2p, weights wp[j] = {g[j], g[j-1]}, j in [0,11]
    f32x2 cA[4] = {}, cB[4] = {}, cC[4] = {}, cD[4] = {};
    #pragma unroll
    for (int w = 0; w < 18; w++) {
        const float u  = U[w], v = V[w];
        const float uu = u * u, vv = v * v;
        #pragma unroll
        for (int p = 0; p < 4; p++) {
            const int j = w - 2 * p;
            if (j < 0 || j > 11) continue;
            const f32x2 wp = wts.wp[j];
            cA[p] += u  * wp;
            cB[p] += v  * wp;
            cC[p] += uu * wp;
            cD[p] += vv * wp;
        }
    }

    // ---- packed SSIM epilogue ----
    float qsum = 0.f;
    #pragma unroll
    for (int p = 0; p < 4; p++) {
        const f32x2 aa = cA[p] * cA[p], bb = cB[p] * cB[p];
        const f32x2 e   = 0.5f * (aa - bb);       // 2*mu1*mu2
        const f32x2 f2  = 0.5f * (aa + bb);       // mu1^2+mu2^2
        const f32x2 t2  = 0.5f * (cC[p] - cD[p]); // 2*s12
        const f32x2 sP  = 0.5f * (cC[p] + cD[p]); // s11+s22
        const f32x2 num = (e + C1f) * (t2 - e + C2f);
        const f32x2 den = (f2 + C1f) * (sP - f2 + C2f);
        qsum += num.x * __builtin_amdgcn_rcpf(den.x);   // den >= C1*C2 > 0
        qsum += num.y * __builtin_amdgcn_rcpf(den.y);
    }

    // ---- block reduction -> one partial per block ----
    #pragma unroll
    for (int off = 32; off; off >>= 1) qsum += __shfl_down(qsum, off);
    __shared__ float wsum[TPB / 64];
    if ((threadIdx.x & 63) == 0) wsum[threadIdx.x >> 6] = qsum;
    __syncthreads();
    if (threadIdx.x == 0) {
        float s = 0.f;
        #pragma unroll
        for (int i = 0; i < TPB / 64; i++) s += wsum[i];
        partial[blockIdx.x] = s;
    }
}

__global__ __launch_bounds__(256) void ssim_reduce(
    const f32x4* __restrict__ partial4, int n4, float* __restrict__ out, float inv_n)
{
    float s = 0.f;
    for (int i = threadIdx.x; i < n4; i += 256) {
        const f32x4 p = partial4[i];
        s += (p.x + p.y) + (p.z + p.w);
    }
    #pragma unroll
    for (int off = 32; off; off >>= 1) s += __shfl_down(s, off);
    __shared__ float ws[4];
    if ((threadIdx.x & 63) == 0) ws[threadIdx.x >> 6] = s;
    __syncthreads();
    if (threadIdx.x == 0) {
        float t = 0.f;
        #pragma unroll
        for (int i = 0; i < 4; i++) t += ws[i];
        out[0] = 1.f - t * inv_n;                 // mean(1-ssim) = 1 - mean(ssim)
    }
}

extern "C" void kernel_launch(void* const* d_in, const int* in_sizes, int n_in,
                              void* d_out, int out_size, void* d_ws, size_t ws_size,
                              hipStream_t stream)
{
    const float* pred = (const float*)d_in[0];
    const float* targ = (const float*)d_in[1];
    float* out = (float*)d_out;
    float* partial = (float*)d_ws;

    const int n      = in_sizes[0];               // B*C*T = 24,576,000
    const int blocks = n / OPT / TPB;             // 12,000 exactly (48 KB d_ws)

    // Gaussian window on host in double (matches numpy), then adjacent pairs.
    double g[11], s = 0.0;
    for (int i = 0; i < 11; i++) { g[i] = exp(-((i - 5) * (i - 5)) / 4.5); s += g[i]; }
    float gw[11];
    for (int i = 0; i < 11; i++) gw[i] = (float)(g[i] / s);
    WP wts;
    for (int j = 0; j < 12; j++) {
        wts.wp[j].x = (j <= 10) ? gw[j] : 0.f;
        wts.wp[j].y = (j >= 1) ? gw[j - 1] : 0.f;
    }

    hipLaunchKernelGGL(ssim_main, dim3(blocks), dim3(TPB), 0, stream,
                       pred, targ, partial, wts);
    hipLaunchKernelGGL(ssim_reduce, dim3(1), dim3(256), 0, stream,
                       (const f32x4*)partial, blocks / 4, out, 1.0f / (float)n);
}